// Round 6
// baseline (1148.724 us; speedup 1.0000x reference)
//
#include <hip/hip_runtime.h>
#include <hip/hip_bf16.h>
#include <stdint.h>

#define NIMG 8
#define NCLS 21
#define HW   4096
#define CF   768
#define NK   2
#define NJ   42
#define NJP  48
#define SINK_MAX 100

using uint32 = unsigned int;
using u16    = unsigned short;

__device__ __forceinline__ float b2f(u16 u){ union{uint32 i; float f;} x; x.i=((uint32)u)<<16; return x.f; }
__device__ __forceinline__ u16 f2b(float f){ union{float f; uint32 i;} x; x.f=f; return (u16)((x.i + 0x7fffu + ((x.i>>16)&1u))>>16); }

template<int BF>
__device__ __forceinline__ float ldin(const void* p, size_t idx){
    if (BF) return b2f(((const u16*)p)[idx]);
    return ((const float*)p)[idx];
}
template<int BF>
__device__ __forceinline__ void stout(void* p, size_t idx, float v){
    if (BF) ((u16*)p)[idx] = f2b(v);
    else    ((float*)p)[idx] = v;
}

// ---------------- 0. dtype detect: bf16 (flag=1) vs f32 (flag=0) -------------
__global__ void k_detect(const void* feat, int* flag){
    __shared__ int cnt;
    if (threadIdx.x == 0) cnt = 0;
    __syncthreads();
    const u16* f = (const u16*)feat;
    int bad = 0;
    for (int i = threadIdx.x; i < 4096; i += 256){
        int ex = (f[i] >> 7) & 0xFF;        // bf16 exponent field
        if (ex >= 160) bad++;               // |v| >= 2^33: impossible for N(0,1) bf16
    }
    atomicAdd(&cnt, bad);
    __syncthreads();
    if (threadIdx.x == 0) *flag = (cnt < 64) ? 1 : 0;
}

// ---------------- 1. per-pixel class assignment (argmax CAM, label-gated) ----
template<int BF>
__global__ void k_seeds(const void* __restrict__ cam, const void* __restrict__ label,
                        int* __restrict__ pix_cls, const int* __restrict__ dflag){
    if (*dflag != BF) return;
    int g = blockIdx.x*256 + threadIdx.x;        // NIMG*HW threads
    int n = g >> 12, p = g & 4095;
    float best = -1e30f; int bel = 0;
    for (int c = 0; c < NCLS; c++){
        float v = ldin<BF>(cam, (size_t)(n*NCLS + c)*HW + p);
        if (v > best){ best = v; bel = c; }      // strict > : first-max tie-break
    }
    pix_cls[g] = (ldin<BF>(label, n*NCLS + bel) > 0.f) ? bel : -1;
}

// ---------------- 2. per-pixel feature norms (f64 accumulate) ----------------
template<int BF>
__global__ void k_norms(const void* __restrict__ feat, float* __restrict__ inv_n,
                        float* __restrict__ inv_ot, const int* __restrict__ dflag){
    if (*dflag != BF) return;
    int g = blockIdx.x*256 + threadIdx.x;        // NIMG*HW threads
    int n = g >> 12, p = g & 4095;
    double s = 0.0;
    for (int k = 0; k < CF; k++){
        double v = (double)ldin<BF>(feat, (size_t)(n*CF + k)*HW + p);
        s += v*v;
    }
    double nr = sqrt(s);
    inv_n [g] = (float)(1.0/fmax(nr, 1e-8));
    inv_ot[g] = (float)(1.0/(nr + 1e-5));
}

// ---------------- 3. per-(n,c): count, ordered pixel list -------------------
// (center init moved into k_kmeans, which reads the packed featCT columns;
//  k_scan only zero-fills centers for the count<2 early-out case)
__global__ void k_scan(const int* __restrict__ pix_cls,
                       int* __restrict__ cnt, int* __restrict__ plist,
                       double* __restrict__ centers){
    int b = blockIdx.x; int n = b / NCLS, c = b % NCLS;
    int lane = threadIdx.x;                       // 64 threads = 1 wave
    int* lst = plist + (size_t)b*HW;
    int count = 0;
    for (int base = 0; base < HW; base += 64){
        int cls = pix_cls[n*HW + base + lane];
        unsigned long long m = __ballot(cls == c);
        int pos = count + __popcll(m & ((1ull<<lane) - 1ull));
        if (cls == c) lst[pos] = base + lane;
        count += __popcll(m);
    }
    if (lane == 0) cnt[b] = count;
    if (count < 2){
        double* C0 = centers + (size_t)b*NK*CF;
        for (int e = lane; e < CF; e += 64){ C0[e] = 0.0; C0[CF+e] = 0.0; }
    }
}

// ---------------- 4. packed order: cstart (prefix of cnt) + pidx ------------
__global__ void k_pidx(const int* __restrict__ cnt, const int* __restrict__ plist,
                       int* __restrict__ cstartg, int* __restrict__ pidx){
    int b = blockIdx.x; int n = b / NCLS, c = b % NCLS;
    int lane = threadIdx.x;                       // 64 threads
    int cbase = 0;
    for (int cc = 0; cc < c; cc++) cbase += cnt[n*NCLS + cc];
    if (lane == 0) cstartg[b] = cbase;
    int m = cnt[b];
    for (int i = lane; i < m; i += 64)
        pidx[n*HW + cbase + i] = plist[(size_t)b*HW + i];
}

// ---------------- 5. pack features: featCT[k][packed_pos], full f32 ---------
// One-time gather (pays the uncoalesced line cost once at GPU-wide
// parallelism); read gathered, write coalesced.
template<int BF>
__global__ void k_pack(const void* __restrict__ feat, const int* __restrict__ pidx,
                       const int* __restrict__ cnt, const int* __restrict__ cstartg,
                       float* __restrict__ featCT, const int* __restrict__ dflag){
    if (*dflag != BF) return;
    int g = blockIdx.x*256 + threadIdx.x;         // NIMG*CF*HW threads
    int n = g / (CF*HW);
    int rem = g - n*(CF*HW);
    int k = rem >> 12;                            // rem / HW
    int pos = rem & 4095;
    int tot = cstartg[n*NCLS + NCLS-1] + cnt[n*NCLS + NCLS-1];
    if (pos < tot)
        featCT[(size_t)g] = ldin<BF>(feat, (size_t)(n*CF + k)*HW + pidx[n*HW + pos]);
}

// -------- 6. k-means (<=10 Lloyd iterations) per (n,c) -----------------------
// round-13 theory: all prior structures gathered per-lane pixel ROWS from
// featT[hw][cf]: one wave-load touched 64 distinct cache lines (16B used of
// 64B) -> ~38k line requests per block-iter through one CU's TA ~= the
// invariant ~30us/iter (VALUBusy ~4%, invariant to prefetch depth and
// reduction style). Fix: class-packed k-major featCT. Pass A: thread owns
// packed pixel cbase+l; wave-load = 64 consecutive floats = 4 full lines
// (16x less line traffic). Pass B: thread owns element e, streams a
// contiguous row (R3's passing accumulation order). Centers f64 in LDS
// broadcast. Dot chains/tie-break/early-exit identical to R3/R4.
__global__ __launch_bounds__(512, 1) void k_kmeans(const int* __restrict__ cnt,
                                                   const int* __restrict__ cstartg,
                                                   const float* __restrict__ featCT,
                                                   double* __restrict__ centers){
    int b = blockIdx.x; int n = b / NCLS;
    int m = cnt[b];
    if (m < 2) return;                            // centers stay zero (k_scan wrote them)
    __shared__ double Cs[2][CF];                  // 12 KB canonical centers
    __shared__ double red[2];
    __shared__ double invn[2];
    __shared__ unsigned char asg[HW];             // 4 KB previous assignment
    __shared__ int chg, ck0i;
    int tid = threadIdx.x, lane = tid & 63;
    int cbase = cstartg[b];
    double* Cg = centers + (size_t)b*NK*CF;
    const float* F = featCT + (size_t)n*CF*HW;    // F[k*HW + cbase + i]
    // init centers from first two packed pixels (== lst[0], lst[1])
    for (int j = tid; j < CF; j += 512){
        Cs[0][j] = (double)F[(size_t)j*HW + cbase];
        Cs[1][j] = (double)F[(size_t)j*HW + cbase + 1];
    }
    for (int i = tid; i < m; i += 512) asg[i] = 255;
    __syncthreads();

    for (int it = 0; it < 10; it++){
        if (tid < 2) red[tid] = 0.0;
        if (tid == 0){ chg = 0; ck0i = 0; }
        __syncthreads();
        // center norms (cold path, once per iter)
        double q0 = 0.0, q1 = 0.0;
        for (int j = tid; j < CF; j += 512){ q0 += Cs[0][j]*Cs[0][j]; q1 += Cs[1][j]*Cs[1][j]; }
        #pragma unroll
        for (int off = 32; off; off >>= 1){ q0 += __shfl_xor(q0, off); q1 += __shfl_xor(q1, off); }
        if (lane == 0){ atomicAdd(&red[0], q0); atomicAdd(&red[1], q1); }
        __syncthreads();
        if (tid == 0){
            invn[0] = 1.0/fmax(sqrt(red[0]), 1e-8);
            invn[1] = 1.0/fmax(sqrt(red[1]), 1e-8);
        }
        __syncthreads();
        double ic0 = invn[0], ic1 = invn[1];

        // ---- pass A: per-thread pixel assignment, coalesced k-major reads ----
        int myC0 = 0, myChg = 0;
        for (int l = tid; l < m; l += 512){
            const float* col = F + cbase + l;
            double s0a=0.0,s0b=0.0,s0c=0.0,s0d=0.0;
            double s1a=0.0,s1b=0.0,s1c=0.0,s1d=0.0;
            #pragma unroll 4
            for (int k = 0; k < CF; k += 4){
                float f0 = col[(size_t)(k+0)*HW];
                float f1 = col[(size_t)(k+1)*HW];
                float f2 = col[(size_t)(k+2)*HW];
                float f3 = col[(size_t)(k+3)*HW];
                s0a += (double)f0*Cs[0][k+0]; s0b += (double)f1*Cs[0][k+1];
                s0c += (double)f2*Cs[0][k+2]; s0d += (double)f3*Cs[0][k+3];
                s1a += (double)f0*Cs[1][k+0]; s1b += (double)f1*Cs[1][k+1];
                s1c += (double)f2*Cs[1][k+2]; s1d += (double)f3*Cs[1][k+3];
            }
            double d0 = (s0a+s0b)+(s0c+s0d);
            double d1 = (s1a+s1b)+(s1c+s1d);
            int a = (d0*ic0 >= d1*ic1) ? 0 : 1;   // argmax, first-max on tie
            if (a == 0) myC0++;
            if (asg[l] != (unsigned char)a){ myChg++; asg[l] = (unsigned char)a; }
        }
        #pragma unroll
        for (int off = 32; off; off >>= 1){
            myC0  += __shfl_xor(myC0,  off);
            myChg += __shfl_xor(myChg, off);
        }
        if (lane == 0){
            if (myC0)  atomicAdd(&ck0i, myC0);
            if (myChg) atomicAdd(&chg,  myChg);
        }
        __syncthreads();
        if (chg == 0) break;                      // exact fixed point: Cs already final
        int c0tot = ck0i;
        double dv0 = fmax((double)c0tot, 1.0);
        double dv1 = fmax((double)(m - c0tot), 1.0);

        // ---- pass B: per-thread-element sums, contiguous streams ----
        {
            const float* r0 = F + (size_t)tid*HW + cbase;
            const float* r1 = F + (size_t)(512 + tid)*HW + cbase;
            float a00 = 0.f, a01 = 0.f, a10 = 0.f, a11 = 0.f;
            #pragma unroll 8
            for (int i = 0; i < m; i++){
                int aa = asg[i];
                float v0 = r0[i];
                float v1 = (tid < 256) ? r1[i] : 0.f;
                if (aa == 0){ a00 += v0; a01 += v1; }
                else        { a10 += v0; a11 += v1; }
            }
            Cs[0][tid] = (double)a00/dv0;
            Cs[1][tid] = (double)a10/dv1;
            if (tid < 256){
                Cs[0][512 + tid] = (double)a01/dv0;
                Cs[1][512 + tid] = (double)a11/dv1;
            }
        }
        __syncthreads();
    }
    for (int j = tid; j < CF; j += 512){ Cg[j] = Cs[0][j]; Cg[CF+j] = Cs[1][j]; }
}

// ---------------- 7. inverse center norms (f64, both epsilon variants) -------
__global__ void k_invc(const double* __restrict__ centers, float* __restrict__ invc_cam,
                       float* __restrict__ invc_ot){
    int b = blockIdx.x;                           // NIMG*NJ blocks, 64 threads
    int lane = threadIdx.x;
    const double* C = centers + (size_t)b*CF;
    double s = 0.0;
    for (int e = lane; e < CF; e += 64) s += C[e]*C[e];
    for (int off = 32; off; off >>= 1) s += __shfl_xor(s, off);
    if (lane == 0){
        double nr = sqrt(s);
        invc_cam[b] = (float)(1.0/fmax(nr, 1e-8));
        invc_ot[b]  = (float)(1.0/(nr + 1e-5));
    }
}

// ---------------- 8. centers f64 -> f32 padded [48,768] ----------------------
__global__ void k_cf32(const double* __restrict__ centers, float* __restrict__ Cf32){
    int n = blockIdx.x; int tid = threadIdx.x;
    for (int idx = tid; idx < NJP*CF; idx += 256){
        int j = idx / CF, e = idx - j*CF;
        float v = (j < NJ) ? (float)centers[((size_t)n*NJ + j)*CF + e] : 0.f;
        Cf32[(size_t)n*NJP*CF + idx] = v;
    }
}

// ---------------- 9. big sim GEMM in f32: D[p][j] = feat[p]·C[j] -------------
// (now reads original feat [cf][hw] directly -- featT is gone; staging loads
//  are coalesced across pixels at each k-row)
template<int BF>
__global__ __launch_bounds__(256) void k_gemmf(const void* __restrict__ feat,
                                               const float* __restrict__ Cf32,
                                               float* __restrict__ D,
                                               const int* __restrict__ dflag){
    if (*dflag != BF) return;
    __shared__ float Fs[128][66];                 // [k][p], padded
    int b = blockIdx.x; int n = b >> 6; int pbase = (b & 63)*64;
    int tid = threadIdx.x, p = tid & 63;
    int jb = __builtin_amdgcn_readfirstlane((tid >> 6)*12);   // wave-uniform j-base
    float acc[12];
    #pragma unroll
    for (int j = 0; j < 12; j++) acc[j] = 0.f;
    for (int kc = 0; kc < CF; kc += 128){
        __syncthreads();
        for (int idx = tid; idx < 128*64; idx += 256){        // 128 k-rows × 64 px
            int kk = idx >> 6, pp = idx & 63;
            Fs[kk][pp] = ldin<BF>(feat, (size_t)(n*CF + kc + kk)*HW + pbase + pp);
        }
        __syncthreads();
        const float* Cb = Cf32 + (size_t)n*NJP*CF + kc;
        for (int k8 = 0; k8 < 128; k8 += 8){
            #pragma unroll
            for (int j = 0; j < 12; j++){
                const float* cr = Cb + (size_t)(jb + j)*CF + k8;
                #pragma unroll
                for (int k = 0; k < 8; k++)
                    acc[j] += Fs[k8 + k][p] * cr[k];
            }
        }
    }
    float* dp = D + ((size_t)(n*HW + pbase + p))*NJP + jb;
    #pragma unroll
    for (int j = 0; j < 12; j++) dp[j] = acc[j];
}

// ---------------- 10. output 0: cam, max-normalized --------------------------
template<int BF>
__global__ __launch_bounds__(256) void k_out0(const float* __restrict__ D,
                                              const float* __restrict__ inv_n,
                                              const float* __restrict__ invc_cam,
                                              const int* __restrict__ cnt,
                                              void* __restrict__ out0,
                                              const int* __restrict__ dflag){
    if (*dflag != BF) return;
    int b = blockIdx.x; int n = b / NCLS, c = b % NCLS;
    __shared__ float wmax[4]; __shared__ float sden;
    int tid = threadIdx.x, lane = tid & 63, w = tid >> 6;
    size_t obase = (size_t)b*HW;
    if (cnt[b] < 2){
        for (int p = tid; p < HW; p += 256) stout<BF>(out0, obase + p, 0.f);
        return;
    }
    float ic0 = invc_cam[n*NJ + 2*c], ic1 = invc_cam[n*NJ + 2*c + 1];
    const float* Dn = D + (size_t)n*HW*NJP;
    float mx = -1e30f;
    for (int p = tid; p < HW; p += 256){
        const float* dp = Dn + (size_t)p*NJP + 2*c;
        float camv = 0.5f*(dp[0]*ic0 + dp[1]*ic1)*inv_n[n*HW + p];
        mx = fmaxf(mx, camv);
    }
    for (int off = 32; off; off >>= 1) mx = fmaxf(mx, __shfl_xor(mx, off));
    if (lane == 0) wmax[w] = mx;
    __syncthreads();
    if (tid == 0) sden = fmaxf(fmaxf(wmax[0], wmax[1]), fmaxf(wmax[2], wmax[3])) + 1e-5f;
    __syncthreads();
    float den = sden;
    for (int p = tid; p < HW; p += 256){
        const float* dp = Dn + (size_t)p*NJP + 2*c;
        float camv = 0.5f*(dp[0]*ic0 + dp[1]*ic1)*inv_n[n*HW + p];
        stout<BF>(out0, obase + p, camv/den);
    }
}

// ---------------- 11. K matrix (scrambled j' = k*21+c) + zero sync bufs ------
__global__ void k_kmat(const float* __restrict__ D, const float* __restrict__ inv_ot,
                       const float* __restrict__ invc_ot, float* __restrict__ Kg,
                       float* __restrict__ errg, int* __restrict__ arrv){
    if (blockIdx.x == 0){
        for (int i = threadIdx.x; i < NIMG*(SINK_MAX+1); i += 256){ errg[i] = 0.f; arrv[i] = 0; }
    }
    int g = blockIdx.x*256 + threadIdx.x;         // NIMG*NCLS*HW threads
    int n = g / (NCLS*HW);
    int rem = g - n*(NCLS*HW);
    int c = rem >> 12, p = rem & 4095;
    const float* dp = D + ((size_t)n*HW + p)*NJP;
    float io = inv_ot[n*HW + p];
    float s0 = dp[c]      * io * invc_ot[n*NJ + c];       // k2=0 -> j'=c  (flat 2c+k order)
    float s1 = dp[21 + c] * io * invc_ot[n*NJ + 21 + c];  // k2=1 -> j'=21+c
    Kg[(size_t)g*2 + 0] = expf((s0 - 1.f)*10.f);
    Kg[(size_t)g*2 + 1] = expf((s1 - 1.f)*10.f);
}

// ---------------- 12. Sinkhorn (faithful while-loop, joint per-image err) ----
template<int BF>
__global__ __launch_bounds__(256) void k_sink(const float* __restrict__ Kg,
                                              float* __restrict__ errg,
                                              int* __restrict__ arrv,
                                              void* __restrict__ d_out,
                                              const int* __restrict__ dflag){
    if (*dflag != BF) return;
    __shared__ float K0s[HW]; __shared__ float K1s[HW]; __shared__ float rs[HW];
    __shared__ float wred[4][3]; __shared__ float sh[3];
    int b = blockIdx.x; int n = b / NCLS;
    int tid = threadIdx.x, lane = tid & 63, w = tid >> 6;
    const float* Kb = Kg + (size_t)b*HW*2;
    for (int p = tid; p < HW; p += 256){ K0s[p] = Kb[p*2]; K1s[p] = Kb[p*2+1]; rs[p] = 1.f; }
    float cc0 = 1.f, cc1 = 1.f, err = 1e30f;
    const float u = 1.f/4096.f;
    int iter = 0;
    __syncthreads();
    while (iter < SINK_MAX && err >= 0.01f){
        float p0 = 0.f, p1 = 0.f, es = 0.f;
        for (int p = tid; p < HW; p += 256){
            float k0 = K0s[p], k1 = K1s[p];
            float rn = u / (k0*cc0 + k1*cc1);
            es += fabsf(rn - rs[p]);
            rs[p] = rn;
            p0 += k0*rn; p1 += k1*rn;
        }
        #pragma unroll
        for (int off = 32; off; off >>= 1){
            p0 += __shfl_xor(p0, off); p1 += __shfl_xor(p1, off); es += __shfl_xor(es, off);
        }
        if (lane == 0){ wred[w][0] = p0; wred[w][1] = p1; wred[w][2] = es; }
        __syncthreads();
        if (tid == 0){
            float P0 = wred[0][0]+wred[1][0]+wred[2][0]+wred[3][0];
            float P1 = wred[0][1]+wred[1][1]+wred[2][1]+wred[3][1];
            float ES = wred[0][2]+wred[1][2]+wred[2][2]+wred[3][2];
            sh[0] = 0.5f/P0; sh[1] = 0.5f/P1;
            int slot = n*(SINK_MAX+1) + iter;
            atomicAdd(&errg[slot], ES);
            __threadfence();
            atomicAdd(&arrv[slot], 1);
            while (__hip_atomic_load(&arrv[slot], __ATOMIC_ACQUIRE, __HIP_MEMORY_SCOPE_AGENT) < NCLS)
                __builtin_amdgcn_s_sleep(8);
            sh[2] = __hip_atomic_load(&errg[slot], __ATOMIC_RELAXED, __HIP_MEMORY_SCOPE_AGENT)
                    * (1.f/((float)NCLS*HW));
        }
        __syncthreads();
        cc0 = sh[0]; cc1 = sh[1]; err = sh[2];
        iter++;
    }
    // out1 starts at element offset NIMG*NCLS*HW in d_out
    size_t o1 = (size_t)NIMG*NCLS*HW + (size_t)b*NK*HW;   // [n][c][k][hw]
    for (int p = tid; p < HW; p += 256){
        float rv = rs[p];
        stout<BF>(d_out, o1 + p,      rv*cc0*K0s[p]);
        stout<BF>(d_out, o1 + HW + p, rv*cc1*K1s[p]);
    }
}

// ---------------- host -------------------------------------------------------
extern "C" void kernel_launch(void* const* d_in, const int* in_sizes, int n_in,
                              void* d_out, int out_size, void* d_ws, size_t ws_size,
                              hipStream_t stream){
    const void* cam   = d_in[0];
    const void* label = d_in[1];
    const void* feat  = d_in[2];

    char* ws = (char*)d_ws; size_t off = 0;
    auto alloc = [&](size_t bytes)->char*{
        char* p = ws + off; off = (off + bytes + 255) & ~(size_t)255; return p;
    };
    int*    dflag    = (int*)   alloc(4);
    float*  featCT   = (float*) alloc((size_t)NIMG*HW*CF*4);   // packed, k-major, f32
    double* centers  = (double*)alloc((size_t)NIMG*NCLS*NK*CF*8);
    float*  Cf32     = (float*) alloc((size_t)NIMG*NJP*CF*4);
    float*  inv_n    = (float*) alloc((size_t)NIMG*HW*4);
    float*  inv_ot   = (float*) alloc((size_t)NIMG*HW*4);
    int*    pix_cls  = (int*)   alloc((size_t)NIMG*HW*4);
    int*    cnt      = (int*)   alloc((size_t)NIMG*NCLS*4);
    int*    plist    = (int*)   alloc((size_t)NIMG*NCLS*HW*4);
    int*    pidx     = (int*)   alloc((size_t)NIMG*HW*4);
    int*    cstartg  = (int*)   alloc((size_t)NIMG*NCLS*4);
    float*  invc_cam = (float*) alloc((size_t)NIMG*NJ*4);
    float*  invc_ot  = (float*) alloc((size_t)NIMG*NJ*4);
    float*  D        = (float*) alloc((size_t)NIMG*HW*NJP*4);
    float*  Kg       = (float*) alloc((size_t)NIMG*NCLS*HW*NK*4);
    float*  errg     = (float*) alloc((size_t)NIMG*(SINK_MAX+1)*4);
    int*    arrv     = (int*)   alloc((size_t)NIMG*(SINK_MAX+1)*4);

    k_detect<<<1, 256, 0, stream>>>(feat, dflag);

    k_seeds<1><<<NIMG*HW/256, 256, 0, stream>>>(cam, label, pix_cls, dflag);
    k_seeds<0><<<NIMG*HW/256, 256, 0, stream>>>(cam, label, pix_cls, dflag);
    k_norms<1><<<NIMG*HW/256, 256, 0, stream>>>(feat, inv_n, inv_ot, dflag);
    k_norms<0><<<NIMG*HW/256, 256, 0, stream>>>(feat, inv_n, inv_ot, dflag);

    k_scan  <<<NIMG*NCLS, 64, 0, stream>>>(pix_cls, cnt, plist, centers);
    k_pidx  <<<NIMG*NCLS, 64, 0, stream>>>(cnt, plist, cstartg, pidx);
    k_pack<1><<<NIMG*CF*HW/256, 256, 0, stream>>>(feat, pidx, cnt, cstartg, featCT, dflag);
    k_pack<0><<<NIMG*CF*HW/256, 256, 0, stream>>>(feat, pidx, cnt, cstartg, featCT, dflag);

    k_kmeans<<<NIMG*NCLS, 512, 0, stream>>>(cnt, cstartg, featCT, centers);
    k_invc  <<<NIMG*NJ, 64, 0, stream>>>(centers, invc_cam, invc_ot);
    k_cf32  <<<NIMG, 256, 0, stream>>>(centers, Cf32);

    k_gemmf<1><<<NIMG*64, 256, 0, stream>>>(feat, Cf32, D, dflag);
    k_gemmf<0><<<NIMG*64, 256, 0, stream>>>(feat, Cf32, D, dflag);

    k_out0<1><<<NIMG*NCLS, 256, 0, stream>>>(D, inv_n, invc_cam, cnt, d_out, dflag);
    k_out0<0><<<NIMG*NCLS, 256, 0, stream>>>(D, inv_n, invc_cam, cnt, d_out, dflag);

    k_kmat  <<<NIMG*NCLS*HW/256, 256, 0, stream>>>(D, inv_ot, invc_ot, Kg, errg, arrv);

    k_sink<1><<<NIMG*NCLS, 256, 0, stream>>>(Kg, errg, arrv, d_out, dflag);
    k_sink<0><<<NIMG*NCLS, 256, 0, stream>>>(Kg, errg, arrv, d_out, dflag);
}

// Round 7
// 631.132 us; speedup vs baseline: 1.8201x; 1.8201x over previous
//
#include <hip/hip_runtime.h>
#include <hip/hip_bf16.h>
#include <stdint.h>

#define NIMG 8
#define NCLS 21
#define HW   4096
#define CF   768
#define NK   2
#define NJ   42
#define NJP  48
#define SINK_MAX 100

using uint32 = unsigned int;
using u16    = unsigned short;

__device__ __forceinline__ float b2f(u16 u){ union{uint32 i; float f;} x; x.i=((uint32)u)<<16; return x.f; }
__device__ __forceinline__ u16 f2b(float f){ union{float f; uint32 i;} x; x.f=f; return (u16)((x.i + 0x7fffu + ((x.i>>16)&1u))>>16); }

template<int BF>
__device__ __forceinline__ float ldin(const void* p, size_t idx){
    if (BF) return b2f(((const u16*)p)[idx]);
    return ((const float*)p)[idx];
}
template<int BF>
__device__ __forceinline__ void stout(void* p, size_t idx, float v){
    if (BF) ((u16*)p)[idx] = f2b(v);
    else    ((float*)p)[idx] = v;
}

// ---------------- 0. dtype detect: bf16 (flag=1) vs f32 (flag=0) -------------
__global__ void k_detect(const void* feat, int* flag){
    __shared__ int cnt;
    if (threadIdx.x == 0) cnt = 0;
    __syncthreads();
    const u16* f = (const u16*)feat;
    int bad = 0;
    for (int i = threadIdx.x; i < 4096; i += 256){
        int ex = (f[i] >> 7) & 0xFF;        // bf16 exponent field
        if (ex >= 160) bad++;               // |v| >= 2^33: impossible for N(0,1) bf16
    }
    atomicAdd(&cnt, bad);
    __syncthreads();
    if (threadIdx.x == 0) *flag = (cnt < 64) ? 1 : 0;
}

// ---------------- 1. per-pixel class assignment (argmax CAM, label-gated) ----
template<int BF>
__global__ void k_seeds(const void* __restrict__ cam, const void* __restrict__ label,
                        int* __restrict__ pix_cls, const int* __restrict__ dflag){
    if (*dflag != BF) return;
    int g = blockIdx.x*256 + threadIdx.x;        // NIMG*HW threads
    int n = g >> 12, p = g & 4095;
    float best = -1e30f; int bel = 0;
    for (int c = 0; c < NCLS; c++){
        float v = ldin<BF>(cam, (size_t)(n*NCLS + c)*HW + p);
        if (v > best){ best = v; bel = c; }      // strict > : first-max tie-break
    }
    pix_cls[g] = (ldin<BF>(label, n*NCLS + bel) > 0.f) ? bel : -1;
}

// ---------------- 2. per-pixel feature norms (f64 accumulate) ----------------
template<int BF>
__global__ void k_norms(const void* __restrict__ feat, float* __restrict__ inv_n,
                        float* __restrict__ inv_ot, const int* __restrict__ dflag){
    if (*dflag != BF) return;
    int g = blockIdx.x*256 + threadIdx.x;        // NIMG*HW threads
    int n = g >> 12, p = g & 4095;
    double s = 0.0;
    for (int k = 0; k < CF; k++){
        double v = (double)ldin<BF>(feat, (size_t)(n*CF + k)*HW + p);
        s += v*v;
    }
    double nr = sqrt(s);
    inv_n [g] = (float)(1.0/fmax(nr, 1e-8));
    inv_ot[g] = (float)(1.0/(nr + 1e-5));
}

// ------- 3. transpose feature [cf,hw] -> featT [hw,cf] in FULL f32 -----------
template<int BF>
__global__ void k_transpose(const void* __restrict__ feat, float* __restrict__ featT,
                            const int* __restrict__ dflag){
    if (*dflag != BF) return;
    __shared__ float tile[64][65];
    int b = blockIdx.x;
    int n   = b / ((CF/64)*(HW/64));
    int rem = b % ((CF/64)*(HW/64));
    int kb = (rem / (HW/64)) * 64;
    int pb = (rem % (HW/64)) * 64;
    int tx = threadIdx.x & 63, ty = threadIdx.x >> 6;
    for (int i = 0; i < 16; i++){
        int k = ty*16 + i;
        tile[tx][k] = ldin<BF>(feat, ((size_t)(n*CF + kb + k))*HW + pb + tx);
    }
    __syncthreads();
    for (int i = 0; i < 16; i++){
        int p = ty*16 + i;
        featT[((size_t)(n*HW + pb + p))*CF + kb + tx] = tile[p][tx];
    }
}

// ---------------- 4. per-(n,c): count, ordered pixel list, init centers ------
__global__ void k_scan(const int* __restrict__ pix_cls, const float* __restrict__ featT,
                       int* __restrict__ cnt, int* __restrict__ plist,
                       double* __restrict__ centers){
    int b = blockIdx.x; int n = b / NCLS, c = b % NCLS;
    int lane = threadIdx.x;                       // 64 threads = 1 wave
    int* lst = plist + (size_t)b*HW;
    int count = 0, i0 = -1, i1 = -1;
    for (int base = 0; base < HW; base += 64){
        int cls = pix_cls[n*HW + base + lane];
        unsigned long long m = __ballot(cls == c);
        int pos = count + __popcll(m & ((1ull<<lane) - 1ull));
        if (cls == c) lst[pos] = base + lane;
        if (i0 < 0){
            if (m){ i0 = base + __ffsll((long long)m) - 1;
                    unsigned long long m2 = m & (m-1);
                    if (m2) i1 = base + __ffsll((long long)m2) - 1; }
        } else if (i1 < 0){
            if (m) i1 = base + __ffsll((long long)m) - 1;
        }
        count += __popcll(m);
    }
    if (lane == 0) cnt[b] = count;
    double* C0 = centers + (size_t)b*NK*CF;
    if (count >= 2){
        const float* r0 = featT + (size_t)(n*HW + i0)*CF;
        const float* r1 = featT + (size_t)(n*HW + i1)*CF;
        for (int e = lane; e < CF; e += 64){ C0[e] = (double)r0[e]; C0[CF+e] = (double)r1[e]; }
    } else {
        for (int e = lane; e < CF; e += 64){ C0[e] = 0.0; C0[CF+e] = 0.0; }
    }
}

// -------- 5. k-means (<=10 Lloyd iterations) per (n,c) -----------------------
// round-14 theory: R1's 262us = DS-pipe pressure of the f64 shfl butterfly
// (96 ds_bpermute per 4-px batch; ~5800 DS instrs/block-iter through the CU's
// one LDS pipe ~= the invariant 26-40us/iter; loads were ALWAYS coalesced).
// Fix: LDS scratch tree = 20 DS instrs/batch: write 8 b64 partials contiguous,
// lgkmcnt(0), read 8 f64 (4x b128, 66-pad), in-lane tree, 3-level shfl in
// 8-lane group + 1 partner shfl, decisions via one __ballot. Loads, partial-dot
// FMA order, accumulation, counters, early-exit identical to the 262us kernel.
// (512,1) = 256-VGPR budget (R2 lesson: no spill possible). LDS 56.3KB.
__global__ __launch_bounds__(512, 1) void k_kmeans(const int* __restrict__ cnt,
                                                   const int* __restrict__ plist,
                                                   const float* __restrict__ featT,
                                                   double* __restrict__ centers){
    int b = blockIdx.x; int n = b / NCLS;
    int m = cnt[b];
    if (m < 2) return;                            // centers stay zero (k_scan wrote them)
    __shared__ double Cs[2][CF];                  // 12 KB (canonical copy)
    __shared__ float  As[2][CF];                  // 6 KB
    __shared__ double part[8][8][66];             // 33.8 KB per-wave reduce scratch
    __shared__ double red[2];
    __shared__ float  ck[2];
    __shared__ double invn[2];
    __shared__ unsigned char asg[HW];             // 4 KB: previous assignment
    __shared__ int chg;
    int tid = threadIdx.x, lane = tid & 63, w = tid >> 6;   // w in [0,8)
    const int* lst = plist + (size_t)b*HW;
    double* Cg = centers + (size_t)b*NK*CF;
    for (int j = tid; j < CF; j += 512){ Cs[0][j] = Cg[j]; Cs[1][j] = Cg[CF+j]; }
    for (int i = tid; i < m; i += 512) asg[i] = 255;
    __syncthreads();
    for (int it = 0; it < 10; it++){
        if (tid < 2){ red[tid] = 0.0; ck[tid] = 0.f; }
        if (tid == 0) chg = 0;
        __syncthreads();
        double q0 = 0.0, q1 = 0.0;
        for (int j = tid; j < CF; j += 512){ q0 += Cs[0][j]*Cs[0][j]; q1 += Cs[1][j]*Cs[1][j]; }
        #pragma unroll
        for (int off = 32; off; off >>= 1){ q0 += __shfl_xor(q0, off); q1 += __shfl_xor(q1, off); }
        if (lane == 0){ atomicAdd(&red[0], q0); atomicAdd(&red[1], q1); }
        for (int j = tid; j < CF; j += 512){ As[0][j] = 0.f; As[1][j] = 0.f; }
        __syncthreads();
        if (tid == 0){
            invn[0] = 1.0/fmax(sqrt(red[0]), 1e-8);
            invn[1] = 1.0/fmax(sqrt(red[1]), 1e-8);
        }
        __syncthreads();
        double ic0 = invn[0], ic1 = invn[1];
        // hoist this lane's center slice into registers (once per Lloyd iter)
        double c0r[12], c1r[12];
        #pragma unroll
        for (int s = 0; s < 3; s++){
            #pragma unroll
            for (int t = 0; t < 4; t++){
                int e = lane*4 + s*256 + t;
                c0r[s*4+t] = Cs[0][e];
                c1r[s*4+t] = Cs[1][e];
            }
        }
        float ac0[12], ac1[12];
        #pragma unroll
        for (int j = 0; j < 12; j++){ ac0[j] = 0.f; ac1[j] = 0.f; }
        int c0n = 0, c1n = 0, myChg = 0;
        // double-buffered 4-pixel batches, wave-stride 8 (batch stride 32)
        float vA[4][12], vB[4][12];
        if (w < m){
            #pragma unroll
            for (int p = 0; p < 4; p++){
                int idx = w + 8*p; int iv = (idx < m) ? idx : (m-1);
                const float* row = featT + (size_t)(n*HW + lst[iv])*CF + lane*4;
                *(float4*)&vA[p][0] = *(const float4*)(row);
                *(float4*)&vA[p][4] = *(const float4*)(row + 256);
                *(float4*)&vA[p][8] = *(const float4*)(row + 512);
            }
        }
        for (int i = w; i < m; i += 32){
            int inext = i + 32;
            if (inext < m){
                #pragma unroll
                for (int p = 0; p < 4; p++){
                    int idx = inext + 8*p; int iv = (idx < m) ? idx : (m-1);
                    const float* row = featT + (size_t)(n*HW + lst[iv])*CF + lane*4;
                    *(float4*)&vB[p][0] = *(const float4*)(row);
                    *(float4*)&vB[p][4] = *(const float4*)(row + 256);
                    *(float4*)&vB[p][8] = *(const float4*)(row + 512);
                }
            }
            double d0[4], d1[4];
            #pragma unroll
            for (int p = 0; p < 4; p++){
                double s0 = 0.0, s1 = 0.0;
                #pragma unroll
                for (int j = 0; j < 12; j++){
                    s0 += (double)vA[p][j]*c0r[j];
                    s1 += (double)vA[p][j]*c1r[j];
                }
                d0[p] = s0; d1[p] = s1;
            }
            // --- LDS scratch tree reduction (replaces 96-bpermute butterfly) ---
            #pragma unroll
            for (int p = 0; p < 4; p++){
                part[w][2*p    ][lane] = d0[p];
                part[w][2*p + 1][lane] = d1[p];
            }
            asm volatile("s_waitcnt lgkmcnt(0)" ::: "memory");
            int s  = lane >> 3;                   // slot 0..7  (= 2p + c)
            int sub = lane & 7;
            const double* pr = &part[w][s][sub*8];
            double t = ((pr[0]+pr[1]) + (pr[2]+pr[3])) + ((pr[4]+pr[5]) + (pr[6]+pr[7]));
            t += __shfl_xor(t, 1);
            t += __shfl_xor(t, 2);
            t += __shfl_xor(t, 4);                // all 8 lanes of group hold slot total
            double tp = __shfl_xor(t, 8);         // partner slot total
            int amine = 0;
            if ((lane & 8) == 0) amine = (t*ic0 >= tp*ic1) ? 0 : 1;  // first-max tie
            unsigned long long bmask = __ballot(((lane & 8) == 0) && amine);
            #pragma unroll
            for (int p = 0; p < 4; p++){
                int idx = i + 8*p;
                if (idx < m){
                    int a = (int)((bmask >> (16*p)) & 1ull);
                    if (lane == 0){
                        if (asg[idx] != (unsigned char)a){ myChg++; asg[idx] = (unsigned char)a; }
                    }
                    if (a == 0){ c0n++;
                        #pragma unroll
                        for (int j = 0; j < 12; j++) ac0[j] += vA[p][j];
                    } else { c1n++;
                        #pragma unroll
                        for (int j = 0; j < 12; j++) ac1[j] += vA[p][j];
                    }
                }
            }
            #pragma unroll
            for (int p = 0; p < 4; p++){
                #pragma unroll
                for (int j = 0; j < 12; j++) vA[p][j] = vB[p][j];
            }
        }
        #pragma unroll
        for (int s = 0; s < 3; s++){
            #pragma unroll
            for (int t = 0; t < 4; t++){
                int e = lane*4 + s*256 + t;
                atomicAdd(&As[0][e], ac0[s*4+t]);
                atomicAdd(&As[1][e], ac1[s*4+t]);
            }
        }
        if (lane == 0){
            atomicAdd(&ck[0], (float)c0n); atomicAdd(&ck[1], (float)c1n);
            if (myChg) atomicAdd(&chg, myChg);
        }
        __syncthreads();
        if (chg == 0) break;                      // exact fixed point: Cs already final
        double dv0 = fmax((double)ck[0], 1.0), dv1 = fmax((double)ck[1], 1.0);
        for (int j = tid; j < CF; j += 512){
            Cs[0][j] = (double)As[0][j]/dv0; Cs[1][j] = (double)As[1][j]/dv1;
        }
        __syncthreads();
    }
    for (int j = tid; j < CF; j += 512){ Cg[j] = Cs[0][j]; Cg[CF+j] = Cs[1][j]; }
}

// ---------------- 6. inverse center norms (f64, both epsilon variants) -------
__global__ void k_invc(const double* __restrict__ centers, float* __restrict__ invc_cam,
                       float* __restrict__ invc_ot){
    int b = blockIdx.x;                           // NIMG*NJ blocks, 64 threads
    int lane = threadIdx.x;
    const double* C = centers + (size_t)b*CF;
    double s = 0.0;
    for (int e = lane; e < CF; e += 64) s += C[e]*C[e];
    for (int off = 32; off; off >>= 1) s += __shfl_xor(s, off);
    if (lane == 0){
        double nr = sqrt(s);
        invc_cam[b] = (float)(1.0/fmax(nr, 1e-8));
        invc_ot[b]  = (float)(1.0/(nr + 1e-5));
    }
}

// ---------------- 7. centers f64 -> f32 padded [48,768] ----------------------
__global__ void k_cf32(const double* __restrict__ centers, float* __restrict__ Cf32){
    int n = blockIdx.x; int tid = threadIdx.x;
    for (int idx = tid; idx < NJP*CF; idx += 256){
        int j = idx / CF, e = idx - j*CF;
        float v = (j < NJ) ? (float)centers[((size_t)n*NJ + j)*CF + e] : 0.f;
        Cf32[(size_t)n*NJP*CF + idx] = v;
    }
}

// ---------------- 8. big sim GEMM in f32: D[p][j] = feat[p]·C[j] -------------
__global__ __launch_bounds__(256) void k_gemmf(const float* __restrict__ featT,
                                               const float* __restrict__ Cf32,
                                               float* __restrict__ D){
    __shared__ float Fs[128][66];                 // [k][p], padded
    int b = blockIdx.x; int n = b >> 6; int pbase = (b & 63)*64;
    int tid = threadIdx.x, p = tid & 63;
    int jb = __builtin_amdgcn_readfirstlane((tid >> 6)*12);   // wave-uniform j-base
    float acc[12];
    #pragma unroll
    for (int j = 0; j < 12; j++) acc[j] = 0.f;
    for (int kc = 0; kc < CF; kc += 128){
        __syncthreads();
        for (int idx = tid; idx < 64*64; idx += 256){         // 64 px × 64 float2
            int pp = idx >> 6, cw = idx & 63;
            float2 wv = *(const float2*)(featT + (size_t)(n*HW + pbase + pp)*CF + kc + cw*2);
            Fs[cw*2    ][pp] = wv.x;
            Fs[cw*2 + 1][pp] = wv.y;
        }
        __syncthreads();
        const float* Cb = Cf32 + (size_t)n*NJP*CF + kc;
        for (int k8 = 0; k8 < 128; k8 += 8){
            #pragma unroll
            for (int j = 0; j < 12; j++){
                const float* cr = Cb + (size_t)(jb + j)*CF + k8;
                #pragma unroll
                for (int k = 0; k < 8; k++)
                    acc[j] += Fs[k8 + k][p] * cr[k];
            }
        }
    }
    float* dp = D + ((size_t)(n*HW + pbase + p))*NJP + jb;
    #pragma unroll
    for (int j = 0; j < 12; j++) dp[j] = acc[j];
}

// ---------------- 9. output 0: cam, max-normalized ---------------------------
template<int BF>
__global__ __launch_bounds__(256) void k_out0(const float* __restrict__ D,
                                              const float* __restrict__ inv_n,
                                              const float* __restrict__ invc_cam,
                                              const int* __restrict__ cnt,
                                              void* __restrict__ out0,
                                              const int* __restrict__ dflag){
    if (*dflag != BF) return;
    int b = blockIdx.x; int n = b / NCLS, c = b % NCLS;
    __shared__ float wmax[4]; __shared__ float sden;
    int tid = threadIdx.x, lane = tid & 63, w = tid >> 6;
    size_t obase = (size_t)b*HW;
    if (cnt[b] < 2){
        for (int p = tid; p < HW; p += 256) stout<BF>(out0, obase + p, 0.f);
        return;
    }
    float ic0 = invc_cam[n*NJ + 2*c], ic1 = invc_cam[n*NJ + 2*c + 1];
    const float* Dn = D + (size_t)n*HW*NJP;
    float mx = -1e30f;
    for (int p = tid; p < HW; p += 256){
        const float* dp = Dn + (size_t)p*NJP + 2*c;
        float camv = 0.5f*(dp[0]*ic0 + dp[1]*ic1)*inv_n[n*HW + p];
        mx = fmaxf(mx, camv);
    }
    for (int off = 32; off; off >>= 1) mx = fmaxf(mx, __shfl_xor(mx, off));
    if (lane == 0) wmax[w] = mx;
    __syncthreads();
    if (tid == 0) sden = fmaxf(fmaxf(wmax[0], wmax[1]), fmaxf(wmax[2], wmax[3])) + 1e-5f;
    __syncthreads();
    float den = sden;
    for (int p = tid; p < HW; p += 256){
        const float* dp = Dn + (size_t)p*NJP + 2*c;
        float camv = 0.5f*(dp[0]*ic0 + dp[1]*ic1)*inv_n[n*HW + p];
        stout<BF>(out0, obase + p, camv/den);
    }
}

// ---------------- 10. K matrix (scrambled j' = k*21+c) + zero sync bufs ------
__global__ void k_kmat(const float* __restrict__ D, const float* __restrict__ inv_ot,
                       const float* __restrict__ invc_ot, float* __restrict__ Kg,
                       float* __restrict__ errg, int* __restrict__ arrv){
    if (blockIdx.x == 0){
        for (int i = threadIdx.x; i < NIMG*(SINK_MAX+1); i += 256){ errg[i] = 0.f; arrv[i] = 0; }
    }
    int g = blockIdx.x*256 + threadIdx.x;         // NIMG*NCLS*HW threads
    int n = g / (NCLS*HW);
    int rem = g - n*(NCLS*HW);
    int c = rem >> 12, p = rem & 4095;
    const float* dp = D + ((size_t)n*HW + p)*NJP;
    float io = inv_ot[n*HW + p];
    float s0 = dp[c]      * io * invc_ot[n*NJ + c];       // k2=0 -> j'=c  (flat 2c+k order)
    float s1 = dp[21 + c] * io * invc_ot[n*NJ + 21 + c];  // k2=1 -> j'=21+c
    Kg[(size_t)g*2 + 0] = expf((s0 - 1.f)*10.f);
    Kg[(size_t)g*2 + 1] = expf((s1 - 1.f)*10.f);
}

// ---------------- 11. Sinkhorn (faithful while-loop, joint per-image err) ----
template<int BF>
__global__ __launch_bounds__(256) void k_sink(const float* __restrict__ Kg,
                                              float* __restrict__ errg,
                                              int* __restrict__ arrv,
                                              void* __restrict__ d_out,
                                              const int* __restrict__ dflag){
    if (*dflag != BF) return;
    __shared__ float K0s[HW]; __shared__ float K1s[HW]; __shared__ float rs[HW];
    __shared__ float wred[4][3]; __shared__ float sh[3];
    int b = blockIdx.x; int n = b / NCLS;
    int tid = threadIdx.x, lane = tid & 63, w = tid >> 6;
    const float* Kb = Kg + (size_t)b*HW*2;
    for (int p = tid; p < HW; p += 256){ K0s[p] = Kb[p*2]; K1s[p] = Kb[p*2+1]; rs[p] = 1.f; }
    float cc0 = 1.f, cc1 = 1.f, err = 1e30f;
    const float u = 1.f/4096.f;
    int iter = 0;
    __syncthreads();
    while (iter < SINK_MAX && err >= 0.01f){
        float p0 = 0.f, p1 = 0.f, es = 0.f;
        for (int p = tid; p < HW; p += 256){
            float k0 = K0s[p], k1 = K1s[p];
            float rn = u / (k0*cc0 + k1*cc1);
            es += fabsf(rn - rs[p]);
            rs[p] = rn;
            p0 += k0*rn; p1 += k1*rn;
        }
        #pragma unroll
        for (int off = 32; off; off >>= 1){
            p0 += __shfl_xor(p0, off); p1 += __shfl_xor(p1, off); es += __shfl_xor(es, off);
        }
        if (lane == 0){ wred[w][0] = p0; wred[w][1] = p1; wred[w][2] = es; }
        __syncthreads();
        if (tid == 0){
            float P0 = wred[0][0]+wred[1][0]+wred[2][0]+wred[3][0];
            float P1 = wred[0][1]+wred[1][1]+wred[2][1]+wred[3][1];
            float ES = wred[0][2]+wred[1][2]+wred[2][2]+wred[3][2];
            sh[0] = 0.5f/P0; sh[1] = 0.5f/P1;
            int slot = n*(SINK_MAX+1) + iter;
            atomicAdd(&errg[slot], ES);
            __threadfence();
            atomicAdd(&arrv[slot], 1);
            while (__hip_atomic_load(&arrv[slot], __ATOMIC_ACQUIRE, __HIP_MEMORY_SCOPE_AGENT) < NCLS)
                __builtin_amdgcn_s_sleep(8);
            sh[2] = __hip_atomic_load(&errg[slot], __ATOMIC_RELAXED, __HIP_MEMORY_SCOPE_AGENT)
                    * (1.f/((float)NCLS*HW));
        }
        __syncthreads();
        cc0 = sh[0]; cc1 = sh[1]; err = sh[2];
        iter++;
    }
    // out1 starts at element offset NIMG*NCLS*HW in d_out
    size_t o1 = (size_t)NIMG*NCLS*HW + (size_t)b*NK*HW;   // [n][c][k][hw]
    for (int p = tid; p < HW; p += 256){
        float rv = rs[p];
        stout<BF>(d_out, o1 + p,      rv*cc0*K0s[p]);
        stout<BF>(d_out, o1 + HW + p, rv*cc1*K1s[p]);
    }
}

// ---------------- host -------------------------------------------------------
extern "C" void kernel_launch(void* const* d_in, const int* in_sizes, int n_in,
                              void* d_out, int out_size, void* d_ws, size_t ws_size,
                              hipStream_t stream){
    const void* cam   = d_in[0];
    const void* label = d_in[1];
    const void* feat  = d_in[2];

    char* ws = (char*)d_ws; size_t off = 0;
    auto alloc = [&](size_t bytes)->char*{
        char* p = ws + off; off = (off + bytes + 255) & ~(size_t)255; return p;
    };
    int*    dflag    = (int*)   alloc(4);
    float*  featT    = (float*) alloc((size_t)NIMG*HW*CF*4);   // f32, not bf16!
    double* centers  = (double*)alloc((size_t)NIMG*NCLS*NK*CF*8);
    float*  Cf32     = (float*) alloc((size_t)NIMG*NJP*CF*4);
    float*  inv_n    = (float*) alloc((size_t)NIMG*HW*4);
    float*  inv_ot   = (float*) alloc((size_t)NIMG*HW*4);
    int*    pix_cls  = (int*)   alloc((size_t)NIMG*HW*4);
    int*    cnt      = (int*)   alloc((size_t)NIMG*NCLS*4);
    int*    plist    = (int*)   alloc((size_t)NIMG*NCLS*HW*4);
    float*  invc_cam = (float*) alloc((size_t)NIMG*NJ*4);
    float*  invc_ot  = (float*) alloc((size_t)NIMG*NJ*4);
    float*  D        = (float*) alloc((size_t)NIMG*HW*NJP*4);
    float*  Kg       = (float*) alloc((size_t)NIMG*NCLS*HW*NK*4);
    float*  errg     = (float*) alloc((size_t)NIMG*(SINK_MAX+1)*4);
    int*    arrv     = (int*)   alloc((size_t)NIMG*(SINK_MAX+1)*4);

    k_detect<<<1, 256, 0, stream>>>(feat, dflag);

    k_seeds<1><<<NIMG*HW/256, 256, 0, stream>>>(cam, label, pix_cls, dflag);
    k_seeds<0><<<NIMG*HW/256, 256, 0, stream>>>(cam, label, pix_cls, dflag);
    k_norms<1><<<NIMG*HW/256, 256, 0, stream>>>(feat, inv_n, inv_ot, dflag);
    k_norms<0><<<NIMG*HW/256, 256, 0, stream>>>(feat, inv_n, inv_ot, dflag);
    k_transpose<1><<<NIMG*(CF/64)*(HW/64), 256, 0, stream>>>(feat, featT, dflag);
    k_transpose<0><<<NIMG*(CF/64)*(HW/64), 256, 0, stream>>>(feat, featT, dflag);

    k_scan  <<<NIMG*NCLS, 64, 0, stream>>>(pix_cls, featT, cnt, plist, centers);
    k_kmeans<<<NIMG*NCLS, 512, 0, stream>>>(cnt, plist, featT, centers);
    k_invc  <<<NIMG*NJ, 64, 0, stream>>>(centers, invc_cam, invc_ot);
    k_cf32  <<<NIMG, 256, 0, stream>>>(centers, Cf32);
    k_gemmf <<<NIMG*64, 256, 0, stream>>>(featT, Cf32, D);

    k_out0<1><<<NIMG*NCLS, 256, 0, stream>>>(D, inv_n, invc_cam, cnt, d_out, dflag);
    k_out0<0><<<NIMG*NCLS, 256, 0, stream>>>(D, inv_n, invc_cam, cnt, d_out, dflag);

    k_kmat  <<<NIMG*NCLS*HW/256, 256, 0, stream>>>(D, inv_ot, invc_ot, Kg, errg, arrv);

    k_sink<1><<<NIMG*NCLS, 256, 0, stream>>>(Kg, errg, arrv, d_out, dflag);
    k_sink<0><<<NIMG*NCLS, 256, 0, stream>>>(Kg, errg, arrv, d_out, dflag);
}